// Round 9
// baseline (60.597 us; speedup 1.0000x reference)
//
#include <hip/hip_runtime.h>
#include <hip/hip_bf16.h>
#include <math.h>

#define LA 1536
#define LS 512
#define LT 2048
#define CC 256
#define NH 4
#define DKH 64
#define NB 4
#define NTA32 (LA / 32)   // 48 audio tiles (32-key)
#define NT32  (LT / 32)   // 64 tiles total
#define SZ ((size_t)NB * LT * CC)

// (1/sqrt(64)) * log2(e): softmax runs in exp2 domain, folded into Q
#define QSCALE 0.1803368801111244f

typedef _Float16 f16;
typedef __attribute__((ext_vector_type(8))) _Float16 f16x8;
typedef __attribute__((ext_vector_type(4))) _Float16 f16x4;
typedef __attribute__((ext_vector_type(4))) float f32x4;
typedef __attribute__((ext_vector_type(16))) float f32x16;

__device__ inline f16x8 cvt8(const float4 a, const float4 b) {
    f16x8 h;
    h[0] = (_Float16)a.x; h[1] = (_Float16)a.y; h[2] = (_Float16)a.z; h[3] = (_Float16)a.w;
    h[4] = (_Float16)b.x; h[5] = (_Float16)b.y; h[6] = (_Float16)b.z; h[7] = (_Float16)b.w;
    return h;
}

// sigma = swap bits 2 and 3 (involution). Reading K row sigma(lo) makes the
// swapped-QK^T C-registers line up exactly with the PV B-fragment k-order
// (HW-verified in round 8).
#define SIG(j) (((j) & ~12) | (((j) & 4) << 1) | (((j) & 8) >> 1))

// ---------------------------------------------------------------------------
// Kernel 1: fused QKV projection, fp16 MFMA (16x16x32), 128x64 tiles.
// Q gets QSCALE folded in. V transposed Vt[(b*NH+h)*DKH+d][l] via LDS.
// (unchanged - proven since round 4/7)
// ---------------------------------------------------------------------------
__global__ __launch_bounds__(256) void qkv_mfma(
    const float* __restrict__ audio, const float* __restrict__ text,
    const float* __restrict__ Wq, const float* __restrict__ bq,
    const float* __restrict__ Wk, const float* __restrict__ bk,
    const float* __restrict__ Wv, const float* __restrict__ bv,
    f16* __restrict__ Qh, f16* __restrict__ Kh, f16* __restrict__ Vth)
{
    __shared__ f16 smem[128 * 64 + 64 * 64];
    f16* As = smem;
    f16* Bs = smem + 128 * 64;

    const int tid = threadIdx.x;
    const int w = tid >> 6, l = tid & 63;
    const int g = l >> 4, r = l & 15;

    const int m0 = blockIdx.x * 128;
    const int n0 = blockIdx.y * 64;
    const int mat = n0 >> 8;          // 0=Q 1=K 2=V
    const int ch0 = n0 & 255;

    const float* W    = (mat == 0) ? Wq : (mat == 1) ? Wk : Wv;
    const float* bias = (mat == 0) ? bq : (mat == 1) ? bk : bv;

    const int b  = m0 >> 11;
    const int l0 = m0 & 2047;

    f32x4 acc[2][4] = {};

    for (int k0 = 0; k0 < CC; k0 += 64) {
        #pragma unroll
        for (int m = 0; m < 4; ++m) {
            const int idx = m * 256 + tid;
            const int row = idx >> 3, c = idx & 7;
            const int lrow = l0 + row;
            const float* src = (lrow < LA)
                ? (audio + ((size_t)b * LA + lrow) * CC + k0 + c * 8)
                : (text  + ((size_t)b * LS + (lrow - LA)) * CC + k0 + c * 8);
            const float4 x0 = *(const float4*)src;
            const float4 x1 = *(const float4*)(src + 4);
            *(f16x8*)(As + row * 64 + ((c ^ (row & 7)) << 3)) = cvt8(x0, x1);
        }
        #pragma unroll
        for (int m = 0; m < 2; ++m) {
            const int idx = m * 256 + tid;
            const int row = idx >> 3, c = idx & 7;
            const float* src = W + (size_t)(ch0 + row) * CC + k0 + c * 8;
            const float4 x0 = *(const float4*)src;
            const float4 x1 = *(const float4*)(src + 4);
            *(f16x8*)(Bs + row * 64 + ((c ^ (row & 7)) << 3)) = cvt8(x0, x1);
        }
        __syncthreads();
        #pragma unroll
        for (int kc = 0; kc < 2; ++kc) {
            f16x8 af[2];
            #pragma unroll
            for (int i = 0; i < 2; ++i) {
                const int row = w * 32 + i * 16 + r;
                const int c = kc * 4 + g;
                af[i] = *(const f16x8*)(As + row * 64 + ((c ^ (row & 7)) << 3));
            }
            f16x8 bf[4];
            #pragma unroll
            for (int j = 0; j < 4; ++j) {
                const int row = j * 16 + r;
                const int c = kc * 4 + g;
                bf[j] = *(const f16x8*)(Bs + row * 64 + ((c ^ (row & 7)) << 3));
            }
            #pragma unroll
            for (int i = 0; i < 2; ++i)
                #pragma unroll
                for (int j = 0; j < 4; ++j)
                    acc[i][j] = __builtin_amdgcn_mfma_f32_16x16x32_f16(af[i], bf[j], acc[i][j], 0, 0, 0);
        }
        __syncthreads();
    }

    float bcol[4];
    #pragma unroll
    for (int j = 0; j < 4; ++j) bcol[j] = bias[ch0 + j * 16 + r];

    if (mat <= 1) {
        f16* Out = (mat == 0) ? Qh : Kh;
        const float osc = (mat == 0) ? QSCALE : 1.0f;
        #pragma unroll
        for (int i = 0; i < 2; ++i)
            #pragma unroll
            for (int e = 0; e < 4; ++e) {
                const int m = m0 + w * 32 + i * 16 + g * 4 + e;
                #pragma unroll
                for (int j = 0; j < 4; ++j)
                    Out[(size_t)m * CC + ch0 + j * 16 + r] =
                        (_Float16)((acc[i][j][e] + bcol[j]) * osc);
            }
    } else {
        f16* Ts = smem;
        #pragma unroll
        for (int i = 0; i < 2; ++i)
            #pragma unroll
            for (int e = 0; e < 4; ++e) {
                const int ml = w * 32 + i * 16 + g * 4 + e;
                #pragma unroll
                for (int j = 0; j < 4; ++j)
                    Ts[(j * 16 + r) * 136 + ml] = (_Float16)(acc[i][j][e] + bcol[j]);
            }
        __syncthreads();
        const int b2 = m0 >> 11, l0m = m0 & 2047;
        #pragma unroll
        for (int u = 0; u < 4; ++u) {
            const int idx = u * 256 + tid;
            const int nl = idx >> 4, mc = idx & 15;
            const f16x8 vv = *(const f16x8*)(Ts + nl * 136 + mc * 8);
            const int nglob = ch0 + nl;
            const int hh = nglob >> 6, dd = nglob & 63;
            *(f16x8*)(Vth + ((size_t)((b2 * NH + hh) * DKH + dd)) * LT + l0m + mc * 8) = vv;
        }
    }
}

// ---------------------------------------------------------------------------
// Kernel 2: flash attention, 32x32x16 MFMA, BARRIER-FREE main loop.
// Grid (64, NH, NB) = 1024 blocks x 256 thr -> 4 blocks/CU, 16 waves/CU.
// Block covers 32 q-rows; 4 waves split the live-tile stream (p = w mod 4),
// each wave reads K / V^T fragments DIRECTLY FROM GLOBAL (K/V total 8 MB,
// fully L2-resident) - no LDS staging, no __syncthreads in the loop.
// sigma key-permutation applied at the global address -> QK^T output regs
// are the PV B-frag (all index algebra HW-verified in round 8).
// One 4-way merge through padded LDS at block end (single barrier).
// ---------------------------------------------------------------------------
__global__ __launch_bounds__(256, 4) void attn_f16(
    const f16* __restrict__ Q, const f16* __restrict__ K,
    const f16* __restrict__ Vt,
    const int* __restrict__ slen, const int* __restrict__ tlen,
    f16* __restrict__ AO)
{
    __shared__ float OcF[3 * 64 * 36];   // 27 KB, stride 36 floats (conflict-free)
    __shared__ float ML[3 * 64 * 2];     // 1.5 KB

    const int tid = threadIdx.x;
    const int w = tid >> 6, l = tid & 63;
    const int lo = l & 31, hi = l >> 5;

    const int q0 = blockIdx.x * 32;
    const int h  = blockIdx.y;
    const int b  = blockIdx.z;

    const int ilen = slen[b];
    const int kcap = LA + tlen[b];
    const int nskip = ilen >> 5;                 // fully-masked audio 32-tiles
    int ntskip = 0;
    if (q0 >= LA) {
        const int skipmax = min(q0 - 31, kcap - 32);
        const int d = skipmax - LA;
        ntskip = (d < 0) ? 0 : ((d >> 5) + 1);
    }
    const int nAudio = NTA32 - nskip;                    // >= 1
    const int nProc  = nAudio + (NT32 - NTA32) - ntskip; // >= 1

    const int qrow = q0 + lo;
    const int slo = SIG(lo);

    // Q B-fragments (QSCALE pre-folded): lane holds Q[qrow][16c + 8hi + e]
    f16x8 qf[4];
    #pragma unroll
    for (int c = 0; c < 4; ++c)
        qf[c] = *(const f16x8*)(Q + ((size_t)(b * LT) + qrow) * CC + h * DKH + 16 * c + 8 * hi);

    // per-lane global bases (k0 added per tile)
    const f16* Kbase = K  + ((size_t)(b * LT) + slo) * CC + h * DKH + 8 * hi;
    const f16* Vbase = Vt + ((size_t)((b * NH + h) * DKH) + lo) * LT + 8 * hi;

    float m_run = -1e30f, l_run = 0.0f;
    f32x16 o[2] = {};   // o[dh]: O^T[d = 32dh + 4hi + (reg&7 expand)][q = qrow]

    for (int p = w; p < nProc; p += 4) {
        const int kt = (p < nAudio) ? (nskip + p) : (NTA32 + ntskip + (p - nAudio));
        const int k0 = kt * 32;

        // ---- S^T = K . Q^T : 4 direct-global A-frag loads + 4 MFMA
        f32x16 s = {};
        #pragma unroll
        for (int c = 0; c < 4; ++c) {
            const f16x8 a = *(const f16x8*)(Kbase + (size_t)k0 * CC + 16 * c);
            s = __builtin_amdgcn_mfma_f32_32x32x16_f16(a, qf[c], s, 0, 0, 0);
        }

        // ---- mask. key(reg) = k0 + 16*(reg>>3) + 8*hi + (reg&7)
        const int mode = (kt < NTA32) ? ((k0 >= ilen) ? 0 : 1)
                                      : ((q0 < LA) ? 0 : 2);
        if (mode == 1) {
            #pragma unroll
            for (int reg = 0; reg < 16; ++reg) {
                const int kk = k0 + 16 * (reg >> 3) + 8 * hi + (reg & 7);
                if (kk < ilen) s[reg] = -INFINITY;
            }
        } else if (mode == 2) {
            #pragma unroll
            for (int reg = 0; reg < 16; ++reg) {
                const int kk = k0 + 16 * (reg >> 3) + 8 * hi + (reg & 7);
                if (!(kk > qrow || kk >= kcap)) s[reg] = -INFINITY;
            }
        }

        // ---- online softmax (exp2 domain, finite sentinel, 1-shfl reduces)
        float mloc = -1e30f;
        #pragma unroll
        for (int reg = 0; reg < 16; ++reg) mloc = fmaxf(mloc, s[reg]);
        mloc = fmaxf(mloc, __shfl_xor(mloc, 32));
        const float m_new = fmaxf(m_run, mloc);

        float ssum = 0.0f;
        f16x8 pb[2];
        #pragma unroll
        for (int s2 = 0; s2 < 2; ++s2)
            #pragma unroll
            for (int e = 0; e < 8; ++e) {
                const float p_ = exp2f(s[8 * s2 + e] - m_new);   // exp2(-inf)=0
                pb[s2][e] = (_Float16)p_;
                ssum += p_;
            }
        ssum += __shfl_xor(ssum, 32);

        if (__all(m_new == m_run)) {          // exact defer (sc == 1)
            l_run += ssum;
        } else {
            const float sc = exp2f(m_run - m_new);    // lane-local (one q/lane)
            l_run = l_run * sc + ssum;
            m_run = m_new;
            #pragma unroll
            for (int dh = 0; dh < 2; ++dh)
                #pragma unroll
                for (int reg = 0; reg < 16; ++reg)
                    o[dh][reg] *= sc;
        }

        // ---- O^T += V^T . P^T : 4 direct-global A-frag loads + 4 MFMA
        #pragma unroll
        for (int s2 = 0; s2 < 2; ++s2)
            #pragma unroll
            for (int dh = 0; dh < 2; ++dh) {
                const f16x8 a = *(const f16x8*)(Vbase + (size_t)(32 * dh) * LT + k0 + 16 * s2);
                o[dh] = __builtin_amdgcn_mfma_f32_32x32x16_f16(a, pb[s2], o[dh], 0, 0, 0);
            }
    }

    // ---- 4-way merge (the only barrier in the kernel)
    if (w != 0) {
        float* dst = OcF + (w - 1) * 64 * 36 + l * 36;
        #pragma unroll
        for (int dh = 0; dh < 2; ++dh)
            #pragma unroll
            for (int u = 0; u < 4; ++u) {
                f32x4 v;
                #pragma unroll
                for (int e = 0; e < 4; ++e) v[e] = o[dh][4 * u + e];
                *(f32x4*)(dst + dh * 16 + 4 * u) = v;
            }
        if (hi == 0) {
            ML[((w - 1) * 64 + lo) * 2 + 0] = m_run;
            ML[((w - 1) * 64 + lo) * 2 + 1] = l_run;
        }
    }
    __syncthreads();

    if (w == 0) {
        float mi[3], li[3];
        float mt = m_run;
        #pragma unroll
        for (int j = 0; j < 3; ++j) {
            mi[j] = ML[(j * 64 + lo) * 2 + 0];
            li[j] = ML[(j * 64 + lo) * 2 + 1];
            mt = fmaxf(mt, mi[j]);
        }
        const float c0 = exp2f(m_run - mt);
        float cj[3], den = l_run * c0;
        #pragma unroll
        for (int j = 0; j < 3; ++j) {
            cj[j] = exp2f(mi[j] - mt);        // mi = -1e30 -> 0 (empty wave)
            den += li[j] * cj[j];
        }
        const float inv = 1.0f / den;         // wave 0 always non-empty -> den>0

        #pragma unroll
        for (int dh = 0; dh < 2; ++dh)
            #pragma unroll
            for (int u = 0; u < 4; ++u) {
                f16x4 outv;
                #pragma unroll
                for (int e = 0; e < 4; ++e) {
                    const int reg = 4 * u + e;
                    float val = o[dh][reg] * c0;
                    #pragma unroll
                    for (int j = 0; j < 3; ++j)
                        val += OcF[j * 64 * 36 + l * 36 + dh * 16 + reg] * cj[j];
                    outv[e] = (_Float16)(val * inv);
                }
                *(f16x4*)(AO + ((size_t)(b * LT) + qrow) * CC + h * DKH
                          + 32 * dh + 8 * u + 4 * hi) = outv;
            }
    }
}

// ---------------------------------------------------------------------------
// Kernel 3: output projection, fp16 MFMA (X already f16), fp32 out.
// (unchanged - proven)
// ---------------------------------------------------------------------------
__global__ __launch_bounds__(256) void out_mfma(
    const f16* __restrict__ X, const float* __restrict__ Wo,
    const float* __restrict__ bo, float* __restrict__ Out)
{
    __shared__ f16 As[128 * 64];
    __shared__ f16 Bs[64 * 64];

    const int tid = threadIdx.x;
    const int w = tid >> 6, l = tid & 63;
    const int g = l >> 4, r = l & 15;

    const int m0 = blockIdx.x * 128;
    const int n0 = blockIdx.y * 64;

    f32x4 acc[2][4] = {};

    for (int k0 = 0; k0 < CC; k0 += 64) {
        #pragma unroll
        for (int m = 0; m < 4; ++m) {
            const int idx = m * 256 + tid;
            const int row = idx >> 3, c = idx & 7;
            *(f16x8*)(As + row * 64 + ((c ^ (row & 7)) << 3)) =
                *(const f16x8*)(X + (size_t)(m0 + row) * CC + k0 + c * 8);
        }
        #pragma unroll
        for (int m = 0; m < 2; ++m) {
            const int idx = m * 256 + tid;
            const int row = idx >> 3, c = idx & 7;
            const float* src = Wo + (size_t)(n0 + row) * CC + k0 + c * 8;
            const float4 x0 = *(const float4*)src;
            const float4 x1 = *(const float4*)(src + 4);
            *(f16x8*)(Bs + row * 64 + ((c ^ (row & 7)) << 3)) = cvt8(x0, x1);
        }
        __syncthreads();
        #pragma unroll
        for (int kc = 0; kc < 2; ++kc) {
            f16x8 af[2];
            #pragma unroll
            for (int i = 0; i < 2; ++i) {
                const int row = w * 32 + i * 16 + r;
                const int c = kc * 4 + g;
                af[i] = *(const f16x8*)(As + row * 64 + ((c ^ (row & 7)) << 3));
            }
            f16x8 bf[4];
            #pragma unroll
            for (int j = 0; j < 4; ++j) {
                const int row = j * 16 + r;
                const int c = kc * 4 + g;
                bf[j] = *(const f16x8*)(Bs + row * 64 + ((c ^ (row & 7)) << 3));
            }
            #pragma unroll
            for (int i = 0; i < 2; ++i)
                #pragma unroll
                for (int j = 0; j < 4; ++j)
                    acc[i][j] = __builtin_amdgcn_mfma_f32_16x16x32_f16(af[i], bf[j], acc[i][j], 0, 0, 0);
        }
        __syncthreads();
    }

    float bcol[4];
    #pragma unroll
    for (int j = 0; j < 4; ++j) bcol[j] = bo[n0 + j * 16 + r];

    #pragma unroll
    for (int i = 0; i < 2; ++i)
        #pragma unroll
        for (int e = 0; e < 4; ++e) {
            const int m = m0 + w * 32 + i * 16 + g * 4 + e;
            #pragma unroll
            for (int j = 0; j < 4; ++j)
                Out[(size_t)m * CC + n0 + j * 16 + r] = acc[i][j][e] + bcol[j];
        }
}

// ---------------------------------------------------------------------------
extern "C" void kernel_launch(void* const* d_in, const int* in_sizes, int n_in,
                              void* d_out, int out_size, void* d_ws, size_t ws_size,
                              hipStream_t stream)
{
    const float* audio = (const float*)d_in[0];
    const float* text  = (const float*)d_in[1];
    const int*   slen  = (const int*)d_in[2];
    const int*   tlen  = (const int*)d_in[3];
    const float* Wq = (const float*)d_in[4];
    const float* bq = (const float*)d_in[5];
    const float* Wk = (const float*)d_in[6];
    const float* bk = (const float*)d_in[7];
    const float* Wv = (const float*)d_in[8];
    const float* bv = (const float*)d_in[9];
    const float* Wo = (const float*)d_in[10];
    const float* bo = (const float*)d_in[11];
    float* out = (float*)d_out;

    f16* Qh  = (f16*)d_ws;
    f16* Kh  = Qh + SZ;
    f16* Vth = Kh + SZ;
    f16* AOh = Vth + SZ;

    qkv_mfma<<<dim3(64, 12), 256, 0, stream>>>(audio, text, Wq, bq, Wk, bk, Wv, bv,
                                               Qh, Kh, Vth);
    attn_f16<<<dim3(LT / 32, NH, NB), 256, 0, stream>>>(Qh, Kh, Vth, slen, tlen, AOh);
    out_mfma<<<dim3(64, 4), 256, 0, stream>>>(AOh, Wo, bo, out);
}

// Round 10
// 54.669 us; speedup vs baseline: 1.1084x; 1.1084x over previous
//
#include <hip/hip_runtime.h>
#include <hip/hip_bf16.h>
#include <math.h>

#define LA 1536
#define LS 512
#define LT 2048
#define CC 256
#define NH 4
#define DKH 64
#define NB 4
#define NT (LT / 64)
#define NTA (LA / 64)     // 24 audio tiles
#define SZ ((size_t)NB * LT * CC)

// (1/sqrt(64)) * log2(e): softmax runs in exp2 domain, folded into Q
#define QSCALE 0.1803368801111244f

typedef _Float16 f16;
typedef __attribute__((ext_vector_type(8))) _Float16 f16x8;
typedef __attribute__((ext_vector_type(4))) _Float16 f16x4;
typedef __attribute__((ext_vector_type(4))) float f32x4;

__device__ inline f16x8 cvt8(const float4 a, const float4 b) {
    f16x8 h;
    h[0] = (_Float16)a.x; h[1] = (_Float16)a.y; h[2] = (_Float16)a.z; h[3] = (_Float16)a.w;
    h[4] = (_Float16)b.x; h[5] = (_Float16)b.y; h[6] = (_Float16)b.z; h[7] = (_Float16)b.w;
    return h;
}

// K-row permutation (HW-verified round 7): store key k at LDS row PROW(k);
// swapped-QK^T C-registers then line up exactly with the PV A-frag k-order.
#define PROW(j) (((j) & 32) | ((((j) >> 2) & 1) << 4) | ((((j) >> 3) & 3) << 2) | ((j) & 3))

// ---------------------------------------------------------------------------
// Kernel 1: FUSED Q+K+V projection. One block computes all three outputs for
// a 64-row x 64-channel slice -> X is staged ONCE (was 3x across blockIdx.y):
// X L3 traffic 96 MB -> 32 MB. fp16 MFMA, fp32 accumulate.
// Q gets QSCALE folded in. V transposed Vt[(b*NH+h)*DKH+d][l] via LDS.
// ---------------------------------------------------------------------------
__global__ __launch_bounds__(256) void qkv_mfma(
    const float* __restrict__ audio, const float* __restrict__ text,
    const float* __restrict__ Wq, const float* __restrict__ bq,
    const float* __restrict__ Wk, const float* __restrict__ bk,
    const float* __restrict__ Wv, const float* __restrict__ bv,
    f16* __restrict__ Qh, f16* __restrict__ Kh, f16* __restrict__ Vth)
{
    __shared__ f16 smem[4 * 4096];   // As | BsQ | BsK | BsV ; Ts aliases front
    f16* As = smem;

    const int tid = threadIdx.x;
    const int w = tid >> 6, l = tid & 63;
    const int g = l >> 4, r = l & 15;

    const int m0  = blockIdx.x * 64;    // 0..8191
    const int ch0 = blockIdx.y * 64;    // 0..255

    const float* Ws[3]   = {Wq, Wk, Wv};
    const float* Bias[3] = {bq, bk, bv};

    const int b  = m0 >> 11;
    const int l0 = m0 & 2047;           // 1536 % 64 == 0 -> clean split

    f32x4 acc[3][4] = {};

    for (int k0 = 0; k0 < CC; k0 += 64) {
        #pragma unroll
        for (int u = 0; u < 2; ++u) {            // As: 64 rows x 8 chunks
            const int idx = u * 256 + tid;
            const int row = idx >> 3, c = idx & 7;
            const int lrow = l0 + row;
            const float* src = (lrow < LA)
                ? (audio + ((size_t)b * LA + lrow) * CC + k0 + c * 8)
                : (text  + ((size_t)b * LS + (lrow - LA)) * CC + k0 + c * 8);
            const float4 x0 = *(const float4*)src;
            const float4 x1 = *(const float4*)(src + 4);
            *(f16x8*)(As + row * 64 + ((c ^ (row & 7)) << 3)) = cvt8(x0, x1);
        }
        #pragma unroll
        for (int mat = 0; mat < 3; ++mat)        // 3 weight tiles
            #pragma unroll
            for (int u = 0; u < 2; ++u) {
                const int idx = u * 256 + tid;
                const int row = idx >> 3, c = idx & 7;
                const float* src = Ws[mat] + (size_t)(ch0 + row) * CC + k0 + c * 8;
                const float4 x0 = *(const float4*)src;
                const float4 x1 = *(const float4*)(src + 4);
                *(f16x8*)(smem + (1 + mat) * 4096 + row * 64 + ((c ^ (row & 7)) << 3)) = cvt8(x0, x1);
            }
        __syncthreads();
        #pragma unroll
        for (int kc = 0; kc < 2; ++kc) {
            const int c = kc * 4 + g;
            const int arow = 16 * w + r;
            const f16x8 af = *(const f16x8*)(As + arow * 64 + ((c ^ (arow & 7)) << 3));
            #pragma unroll
            for (int mat = 0; mat < 3; ++mat)
                #pragma unroll
                for (int j = 0; j < 4; ++j) {
                    const int brow = j * 16 + r;
                    const f16x8 bf = *(const f16x8*)(smem + (1 + mat) * 4096
                                                     + brow * 64 + ((c ^ (brow & 7)) << 3));
                    acc[mat][j] = __builtin_amdgcn_mfma_f32_16x16x32_f16(af, bf, acc[mat][j], 0, 0, 0);
                }
        }
        __syncthreads();
    }

    float bcol[3][4];
    #pragma unroll
    for (int mat = 0; mat < 3; ++mat)
        #pragma unroll
        for (int j = 0; j < 4; ++j) bcol[mat][j] = Bias[mat][ch0 + j * 16 + r];

    // Q (xQSCALE) and K: direct stores
    #pragma unroll
    for (int e = 0; e < 4; ++e) {
        const int m = m0 + 16 * w + 4 * g + e;
        #pragma unroll
        for (int j = 0; j < 4; ++j) {
            Qh[(size_t)m * CC + ch0 + j * 16 + r] =
                (_Float16)((acc[0][j][e] + bcol[0][j]) * QSCALE);
            Kh[(size_t)m * CC + ch0 + j * 16 + r] =
                (_Float16)(acc[1][j][e] + bcol[1][j]);
        }
    }

    // V: transpose through Ts[64 n][72 m-pad] (aliases As+BsQ), coalesced store
    f16* Ts = smem;
    #pragma unroll
    for (int e = 0; e < 4; ++e) {
        const int ml = 16 * w + 4 * g + e;
        #pragma unroll
        for (int j = 0; j < 4; ++j)
            Ts[(j * 16 + r) * 72 + ml] = (_Float16)(acc[2][j][e] + bcol[2][j]);
    }
    __syncthreads();
    #pragma unroll
    for (int u = 0; u < 2; ++u) {
        const int idx = u * 256 + tid;
        const int nl = idx >> 3, mc = idx & 7;
        const f16x8 vv = *(const f16x8*)(Ts + nl * 72 + mc * 8);
        const int nglob = ch0 + nl;
        const int hh = nglob >> 6, dd = nglob & 63;
        *(f16x8*)(Vth + ((size_t)((b * NH + hh) * DKH + dd)) * LT + l0 + mc * 8) = vv;
    }
}

// ---------------------------------------------------------------------------
// Kernel 2: flash attention, fp16 MFMA, inverted mask.
// R4 skeleton (512 thr, 2 tile-split groups x 4 waves, 16 q/wave, single
// K/V buffer per group, reg-staged next tile, 2 barriers/iter) +
//  - PROW K-row permutation -> P stays in registers (no Ps buffer; LDS 32 KB)
//  - s_setprio(1) around MFMA clusters (groups run phase-offset)
//  - exp2-domain softmax (QSCALE pre-folded), exact defer-rescale, tile skips
// Group merge through union over the (dead) K/V buffers.
// ---------------------------------------------------------------------------
__global__ __launch_bounds__(512) void attn_f16(
    const f16* __restrict__ Q, const f16* __restrict__ K,
    const f16* __restrict__ Vt,
    const int* __restrict__ slen, const int* __restrict__ tlen,
    f16* __restrict__ AO)
{
    __shared__ __align__(16) f16 Ks[2][4096];    // [group][row_prow*64 + d']
    __shared__ __align__(16) f16 Vts[2][4096];   // [group][d*64 + key']

    const int tid = threadIdx.x;
    const int w = tid >> 6, l = tid & 63;
    const int gid = w >> 2, wg = w & 3;
    const int g = l >> 4, r = l & 15;
    const int tg = tid & 255;

    const int q0 = blockIdx.x * 64;
    const int h  = blockIdx.y;
    const int b  = blockIdx.z;

    const int ilen = slen[b];
    const int kcap = LA + tlen[b];
    const int nskip = ilen >> 6;
    int ntskip = 0;
    if (q0 >= LA) {
        const int skipmax = min(q0 - 63, kcap - 64);
        const int d = skipmax - LA;
        ntskip = (d < 0) ? 0 : ((d >> 6) + 1);
    }
    const int nAudio = NTA - nskip;                  // >= 1
    const int nProc  = nAudio + (NT - NTA) - ntskip; // >= 2
    const int nIter  = (nProc + 1) >> 1;

    const int qrow = q0 + 16 * wg + r;

    // Q fragment (QSCALE pre-folded by qkv_mfma)
    f16x8 qf[2];
    #pragma unroll
    for (int ch = 0; ch < 2; ++ch)
        qf[ch] = *(const f16x8*)(Q + ((size_t)(b * LT) + qrow) * CC + h * DKH + ch * 32 + g * 8);

    // staging (per group: 256 threads, rows srow0 / srow0+32, chunk scc)
    const int srow0 = tg >> 3, scc = tg & 7;
    const int srow1 = srow0 + 32;
    const int kp0 = PROW(srow0), kp1 = PROW(srow1);
    const int kdst0 = kp0 * 64 + ((scc ^ (kp0 & 7)) << 3);
    const int kdst1 = kp1 * 64 + ((scc ^ (kp1 & 7)) << 3);
    const int vdst0 = srow0 * 64 + ((scc ^ (srow0 & 7)) << 3);
    const int vdst1 = srow1 * 64 + ((scc ^ (srow1 & 7)) << 3);

    #define TILE_OF(p) ((p) < nAudio ? (nskip + (p)) : (NTA + ntskip + ((p) - nAudio)))

    {   // prologue: stage this group's first tile
        const int k0 = TILE_OF(gid) * 64;
        *(f16x8*)(Ks[gid] + kdst0) =
            *(const f16x8*)(K + ((size_t)(b * LT) + k0 + srow0) * CC + h * DKH + scc * 8);
        *(f16x8*)(Ks[gid] + kdst1) =
            *(const f16x8*)(K + ((size_t)(b * LT) + k0 + srow1) * CC + h * DKH + scc * 8);
        *(f16x8*)(Vts[gid] + vdst0) =
            *(const f16x8*)(Vt + ((size_t)((b * NH + h) * DKH) + srow0) * LT + k0 + scc * 8);
        *(f16x8*)(Vts[gid] + vdst1) =
            *(const f16x8*)(Vt + ((size_t)((b * NH + h) * DKH) + srow1) * LT + k0 + scc * 8);
    }

    float m_run = -1e30f, l_run = 0.0f;
    f32x4 o[4] = {};   // o[dsb][e]: O[q = 4g+e][d = 16*dsb + r]

    for (int i = 0; i < nIter; ++i) {
        __syncthreads();                       // A: staged tiles visible
        const int pcur = 2 * i + gid;
        const bool curV = pcur < nProc;
        const bool nxtV = (pcur + 2) < nProc;

        f16x8 kr0, kr1, vr0, vr1;
        if (nxtV) {     // issue next-tile loads early (hide HBM/L2 latency)
            const int kn = TILE_OF(pcur + 2) * 64;
            kr0 = *(const f16x8*)(K + ((size_t)(b * LT) + kn + srow0) * CC + h * DKH + scc * 8);
            kr1 = *(const f16x8*)(K + ((size_t)(b * LT) + kn + srow1) * CC + h * DKH + scc * 8);
            vr0 = *(const f16x8*)(Vt + ((size_t)((b * NH + h) * DKH) + srow0) * LT + kn + scc * 8);
            vr1 = *(const f16x8*)(Vt + ((size_t)((b * NH + h) * DKH) + srow1) * LT + kn + scc * 8);
        }

        if (curV) {
            const int kt = TILE_OF(pcur);
            const int k0 = kt * 64;
            const f16* Kb = Ks[gid];
            const f16* Vb = Vts[gid];

            // ---- S^T = K . Q^T (K rows PROW-permuted)
            f32x4 sacc[4] = {};
            __builtin_amdgcn_s_setprio(1);
            #pragma unroll
            for (int s = 0; s < 4; ++s) {
                const int arow = 16 * s + r;
                #pragma unroll
                for (int ch = 0; ch < 2; ++ch) {
                    const f16x8 a = *(const f16x8*)(Kb + arow * 64 + (((ch * 4 + g) ^ (arow & 7)) << 3));
                    sacc[s] = __builtin_amdgcn_mfma_f32_16x16x32_f16(a, qf[ch], sacc[s], 0, 0, 0);
                }
            }
            __builtin_amdgcn_s_setprio(0);

            // ---- mask; key of sacc[s][e] = kb + 32*(s>>1) + 4*(s&1) + e
            const int mode = (kt < NTA) ? ((k0 >= ilen) ? 0 : 1)
                                        : ((q0 < LA) ? 0 : 2);
            const int kb = k0 + 8 * g;
            float sv[16];
            if (mode == 0) {
                #pragma unroll
                for (int s = 0; s < 4; ++s)
                    #pragma unroll
                    for (int e = 0; e < 4; ++e) sv[s * 4 + e] = sacc[s][e];
            } else if (mode == 1) {
                #pragma unroll
                for (int s = 0; s < 4; ++s)
                    #pragma unroll
                    for (int e = 0; e < 4; ++e) {
                        const int kk = kb + 32 * (s >> 1) + 4 * (s & 1) + e;
                        sv[s * 4 + e] = (kk >= ilen) ? sacc[s][e] : -INFINITY;
                    }
            } else {
                #pragma unroll
                for (int s = 0; s < 4; ++s)
                    #pragma unroll
                    for (int e = 0; e < 4; ++e) {
                        const int kk = kb + 32 * (s >> 1) + 4 * (s & 1) + e;
                        sv[s * 4 + e] = (kk > qrow || kk >= kcap) ? sacc[s][e] : -INFINITY;
                    }
            }

            // ---- online softmax, exp2 domain, finite sentinel
            float mloc = -1e30f;
            #pragma unroll
            for (int u = 0; u < 16; ++u) mloc = fmaxf(mloc, sv[u]);
            mloc = fmaxf(mloc, __shfl_xor(mloc, 16));
            mloc = fmaxf(mloc, __shfl_xor(mloc, 32));
            const float m_new = fmaxf(m_run, mloc);

            float ssum = 0.0f;
            f16x4 ph[4];
            #pragma unroll
            for (int s = 0; s < 4; ++s)
                #pragma unroll
                for (int e = 0; e < 4; ++e) {
                    const float p = exp2f(sv[s * 4 + e] - m_new);   // exp2(-inf)=0
                    ph[s][e] = (_Float16)p;
                    ssum += p;
                }
            ssum += __shfl_xor(ssum, 16);
            ssum += __shfl_xor(ssum, 32);

            if (__all(m_new == m_run)) {           // exact defer (sc==1)
                l_run += ssum;
            } else {
                const float sc = exp2f(m_run - m_new);
                l_run = l_run * sc + ssum;
                m_run = m_new;
                #pragma unroll
                for (int e = 0; e < 4; ++e) {
                    const float scr = __shfl(sc, 4 * g + e);
                    #pragma unroll
                    for (int dsb = 0; dsb < 4; ++dsb) o[dsb][e] *= scr;
                }
            }

            // ---- O += P . V  (A-frag = own registers, thanks to PROW)
            __builtin_amdgcn_s_setprio(1);
            #pragma unroll
            for (int ch = 0; ch < 2; ++ch) {
                f16x8 a;
                #pragma unroll
                for (int e = 0; e < 4; ++e) { a[e] = ph[2 * ch][e]; a[4 + e] = ph[2 * ch + 1][e]; }
                #pragma unroll
                for (int dsb = 0; dsb < 4; ++dsb) {
                    const int vrow = 16 * dsb + r;
                    const f16x8 bf = *(const f16x8*)(Vb + vrow * 64 + (((ch * 4 + g) ^ (vrow & 7)) << 3));
                    o[dsb] = __builtin_amdgcn_mfma_f32_16x16x32_f16(a, bf, o[dsb], 0, 0, 0);
                }
            }
            __builtin_amdgcn_s_setprio(0);
        }

        __syncthreads();                       // B: group's LDS reads done
        if (nxtV) {
            *(f16x8*)(Ks[gid] + kdst0)  = kr0;
            *(f16x8*)(Ks[gid] + kdst1)  = kr1;
            *(f16x8*)(Vts[gid] + vdst0) = vr0;
            *(f16x8*)(Vts[gid] + vdst1) = vr1;
        }
    }

    // ---- merge group partials through union over dead K/V buffers
    float* OcF = (float*)&Ks[0][0];    // [wg*4+dsb][lane*4+e] : 16 KB
    float* ML1 = (float*)&Vts[0][0];   // [qloc][2] : 512 B
    if (gid == 1) {
        #pragma unroll
        for (int dsb = 0; dsb < 4; ++dsb)
            *(f32x4*)(OcF + ((wg * 4 + dsb) << 8) + (l << 2)) = o[dsb];
        if (g == 0) {
            ML1[(16 * wg + r) * 2 + 0] = m_run;
            ML1[(16 * wg + r) * 2 + 1] = l_run;
        }
    }
    __syncthreads();

    if (gid == 0) {
        #pragma unroll
        for (int e = 0; e < 4; ++e) {
            const int qloc = 16 * wg + 4 * g + e;
            const float m0v = __shfl(m_run, 4 * g + e);
            const float l0v = __shfl(l_run, 4 * g + e);
            const float m1v = ML1[qloc * 2 + 0];
            const float l1v = ML1[qloc * 2 + 1];
            const float mt = fmaxf(m0v, m1v);
            const float c0 = exp2f(m0v - mt);
            const float c1 = exp2f(m1v - mt);
            const float inv = 1.0f / (l0v * c0 + l1v * c1);
            #pragma unroll
            for (int dsb = 0; dsb < 4; ++dsb) {
                const float v = (o[dsb][e] * c0
                               + OcF[((wg * 4 + dsb) << 8) + (l << 2) + e] * c1) * inv;
                AO[((size_t)(b * LT) + q0 + qloc) * CC + h * DKH + 16 * dsb + r] = (_Float16)v;
            }
        }
    }
    #undef TILE_OF
}

// ---------------------------------------------------------------------------
// Kernel 3: output projection, fp16 MFMA (X already f16), fp32 out.
// (unchanged - proven)
// ---------------------------------------------------------------------------
__global__ __launch_bounds__(256) void out_mfma(
    const f16* __restrict__ X, const float* __restrict__ Wo,
    const float* __restrict__ bo, float* __restrict__ Out)
{
    __shared__ f16 As[128 * 64];
    __shared__ f16 Bs[64 * 64];

    const int tid = threadIdx.x;
    const int w = tid >> 6, l = tid & 63;
    const int g = l >> 4, r = l & 15;

    const int m0 = blockIdx.x * 128;
    const int n0 = blockIdx.y * 64;

    f32x4 acc[2][4] = {};

    for (int k0 = 0; k0 < CC; k0 += 64) {
        #pragma unroll
        for (int m = 0; m < 4; ++m) {
            const int idx = m * 256 + tid;
            const int row = idx >> 3, c = idx & 7;
            *(f16x8*)(As + row * 64 + ((c ^ (row & 7)) << 3)) =
                *(const f16x8*)(X + (size_t)(m0 + row) * CC + k0 + c * 8);
        }
        #pragma unroll
        for (int m = 0; m < 2; ++m) {
            const int idx = m * 256 + tid;
            const int row = idx >> 3, c = idx & 7;
            const float* src = Wo + (size_t)(n0 + row) * CC + k0 + c * 8;
            const float4 x0 = *(const float4*)src;
            const float4 x1 = *(const float4*)(src + 4);
            *(f16x8*)(Bs + row * 64 + ((c ^ (row & 7)) << 3)) = cvt8(x0, x1);
        }
        __syncthreads();
        #pragma unroll
        for (int kc = 0; kc < 2; ++kc) {
            f16x8 af[2];
            #pragma unroll
            for (int i = 0; i < 2; ++i) {
                const int row = w * 32 + i * 16 + r;
                const int c = kc * 4 + g;
                af[i] = *(const f16x8*)(As + row * 64 + ((c ^ (row & 7)) << 3));
            }
            f16x8 bf[4];
            #pragma unroll
            for (int j = 0; j < 4; ++j) {
                const int row = j * 16 + r;
                const int c = kc * 4 + g;
                bf[j] = *(const f16x8*)(Bs + row * 64 + ((c ^ (row & 7)) << 3));
            }
            #pragma unroll
            for (int i = 0; i < 2; ++i)
                #pragma unroll
                for (int j = 0; j < 4; ++j)
                    acc[i][j] = __builtin_amdgcn_mfma_f32_16x16x32_f16(af[i], bf[j], acc[i][j], 0, 0, 0);
        }
        __syncthreads();
    }

    float bcol[4];
    #pragma unroll
    for (int j = 0; j < 4; ++j) bcol[j] = bo[n0 + j * 16 + r];

    #pragma unroll
    for (int i = 0; i < 2; ++i)
        #pragma unroll
        for (int e = 0; e < 4; ++e) {
            const int m = m0 + w * 32 + i * 16 + g * 4 + e;
            #pragma unroll
            for (int j = 0; j < 4; ++j)
                Out[(size_t)m * CC + n0 + j * 16 + r] = acc[i][j][e] + bcol[j];
        }
}

// ---------------------------------------------------------------------------
extern "C" void kernel_launch(void* const* d_in, const int* in_sizes, int n_in,
                              void* d_out, int out_size, void* d_ws, size_t ws_size,
                              hipStream_t stream)
{
    const float* audio = (const float*)d_in[0];
    const float* text  = (const float*)d_in[1];
    const int*   slen  = (const int*)d_in[2];
    const int*   tlen  = (const int*)d_in[3];
    const float* Wq = (const float*)d_in[4];
    const float* bq = (const float*)d_in[5];
    const float* Wk = (const float*)d_in[6];
    const float* bk = (const float*)d_in[7];
    const float* Wv = (const float*)d_in[8];
    const float* bv = (const float*)d_in[9];
    const float* Wo = (const float*)d_in[10];
    const float* bo = (const float*)d_in[11];
    float* out = (float*)d_out;

    f16* Qh  = (f16*)d_ws;
    f16* Kh  = Qh + SZ;
    f16* Vth = Kh + SZ;
    f16* AOh = Vth + SZ;

    qkv_mfma<<<dim3(128, 4), 256, 0, stream>>>(audio, text, Wq, bq, Wk, bk, Wv, bv,
                                               Qh, Kh, Vth);
    attn_f16<<<dim3(LT / 64, NH, NB), 512, 0, stream>>>(Qh, Kh, Vth, slen, tlen, AOh);
    out_mfma<<<dim3(64, 4), 256, 0, stream>>>(AOh, Wo, bo, out);
}